// Round 1
// baseline (446.157 us; speedup 1.0000x reference)
//
#include <hip/hip_runtime.h>
#include <math.h>

#define BB 256
#define VV 4096
#define DD 64
#define VCHUNK 128
#define NCHUNK (VV / VCHUNK)

typedef __attribute__((address_space(3))) void lds_void_t;
typedef const __attribute__((address_space(1))) void gvoid_t;

// ---------------------------------------------------------------------------
// Kernel 1: per (a) block, compute top-2 over v of sim[b,a,v] for all b.
// Stores transposed: max0T[a*256 + b], max1T[a*256 + b].
// ---------------------------------------------------------------------------
__global__ __launch_bounds__(512) void topk_sim_kernel(
    const float* __restrict__ F, const float* __restrict__ lan,
    float* __restrict__ max0T, float* __restrict__ max1T)
{
  extern __shared__ __align__(16) char smem[];
  float* lanT = (float*)smem;        // [64][256] fp32 = 64 KB, lanT[d][b]
  char*  fbase = smem + 65536;       // 8 waves x 2 bufs x 4096 B = 64 KB

  const int t = threadIdx.x;
  const int a = blockIdx.x;
  const int wave = t >> 6;
  const int lane = t & 63;
  const int lane4 = lane << 2;       // this lane owns b = lane4 .. lane4+3

  // ---- stage lan transposed into lanT[d][b] (one-time) ----
  {
    const int b = t >> 1;
    const int h = t & 1;
    const float4* src = (const float4*)(lan + b * DD + h * 32);
#pragma unroll
    for (int k = 0; k < 8; ++k) {
      float4 v4 = src[k];
      int d0 = h * 32 + (k << 2);
      lanT[(d0 + 0) * BB + b] = v4.x;   // bank = b%32 -> 2-way across wave: free
      lanT[(d0 + 1) * BB + b] = v4.y;
      lanT[(d0 + 2) * BB + b] = v4.z;
      lanT[(d0 + 3) * BB + b] = v4.w;
    }
  }

  const char* gFa = (const char*)(F + (size_t)a * VV * DD);

  // wave-private F staging: wave w owns rows [w*16, w*16+16) of each 128-row chunk.
  // LDS dest must be wave-uniform (HW adds lane*16 itself).
  auto stage = [&](int ch, int p) {
    char* dst = fbase + (((wave << 1) | p) << 12);               // 4 KB region
    const char* g = gFa + (size_t)(ch * VCHUNK + wave * 16) * DD * 4;
#pragma unroll
    for (int i = 0; i < 4; ++i) {
      __builtin_amdgcn_global_load_lds(
          (gvoid_t*)(g + i * 1024 + lane * 16),
          (lds_void_t*)(dst + i * 1024),
          16, 0, 0);
    }
  };

  stage(0, 0);
  __syncthreads();   // lanT ready (also drains chunk-0 loads)

  float m0[4], m1[4];
#pragma unroll
  for (int c = 0; c < 4; ++c) { m0[c] = -INFINITY; m1[c] = -INFINITY; }

  for (int ch = 0; ch < NCHUNK; ++ch) {
    const int p = ch & 1;
    if (ch + 1 < NCHUNK) {
      stage(ch + 1, p ^ 1);                       // prefetch next chunk
      asm volatile("s_waitcnt vmcnt(4)" ::: "memory");   // wait current, keep 4 in flight
    } else {
      asm volatile("s_waitcnt vmcnt(0)" ::: "memory");
    }
    __builtin_amdgcn_sched_barrier(0);

    const float* Fc = (const float*)(fbase + (((wave << 1) | p) << 12));
#pragma unroll
    for (int g = 0; g < 2; ++g) {
      const float* Fg = Fc + (g << 3) * DD;       // 8 local v-rows
      float acc[8][4];
#pragma unroll
      for (int vi = 0; vi < 8; ++vi)
#pragma unroll
        for (int c = 0; c < 4; ++c) acc[vi][c] = 0.0f;

#pragma unroll 2
      for (int dd = 0; dd < DD; dd += 4) {
        float lq[4][4];
#pragma unroll
        for (int q = 0; q < 4; ++q) {
          float4 l4 = *(const float4*)&lanT[(dd + q) * BB + lane4];  // conflict-free
          lq[q][0] = l4.x; lq[q][1] = l4.y; lq[q][2] = l4.z; lq[q][3] = l4.w;
        }
#pragma unroll
        for (int vi = 0; vi < 8; ++vi) {
          float4 f4 = *(const float4*)&Fg[vi * DD + dd];  // wave-uniform: broadcast
#pragma unroll
          for (int c = 0; c < 4; ++c) {
            acc[vi][c] += f4.x * lq[0][c];
            acc[vi][c] += f4.y * lq[1][c];
            acc[vi][c] += f4.z * lq[2][c];
            acc[vi][c] += f4.w * lq[3][c];
          }
        }
      }

      // fold this v-group into running top-2 (values only; top_k needs values)
#pragma unroll
      for (int vi = 0; vi < 8; ++vi)
#pragma unroll
        for (int c = 0; c < 4; ++c) {
          float v = acc[vi][c];
          float nm1 = (v > m0[c]) ? m0[c] : fmaxf(m1[c], v);
          m0[c] = fmaxf(m0[c], v);
          m1[c] = nm1;
        }
    }
  }

  // ---- cross-wave top-2 merge via LDS ----
  __syncthreads();
  float* part = (float*)fbase;  // [8][256][2] fp32 = 16 KB (reuse F region)
#pragma unroll
  for (int c = 0; c < 4; ++c) {
    int b = lane4 + c;
    part[((wave << 8) + b) * 2 + 0] = m0[c];
    part[((wave << 8) + b) * 2 + 1] = m1[c];
  }
  __syncthreads();
  if (t < BB) {
    float M0 = -INFINITY, M1 = -INFINITY;
#pragma unroll
    for (int w = 0; w < 8; ++w) {
      float a0 = part[((w << 8) + t) * 2 + 0];
      float a1 = part[((w << 8) + t) * 2 + 1];
      // top-2 of {M0,M1,a0,a1}: second = max(min(M0,a0), max(M1,a1))
      float nM1 = fmaxf(fminf(M0, a0), fmaxf(M1, a1));
      M0 = fmaxf(M0, a0);
      M1 = nM1;
    }
    max0T[a * BB + t] = M0;
    max1T[a * BB + t] = M1;
  }
}

// ---------------------------------------------------------------------------
// Kernel 2: per row b, LSE over 511 logits = [max0[b][:], max1[b][a!=b]],
// loss_b = LSE - max0[b][b].  Arrays stored transposed [a][b].
// ---------------------------------------------------------------------------
__global__ __launch_bounds__(256) void lse_kernel(
    const float* __restrict__ max0T, const float* __restrict__ max1T,
    float* __restrict__ lossb)
{
  __shared__ float red[256];
  __shared__ float diag;
  const int b = blockIdx.x;
  const int t = threadIdx.x;     // t = a
  float x0 = max0T[t * BB + b];
  float x1 = (t == b) ? -INFINITY : max1T[t * BB + b];
  if (t == b) diag = x0;
  red[t] = fmaxf(x0, x1);
  __syncthreads();
  for (int s = 128; s > 0; s >>= 1) {
    if (t < s) red[t] = fmaxf(red[t], red[t + s]);
    __syncthreads();
  }
  float M = red[0];
  __syncthreads();
  float e = expf(x0 - M) + ((t == b) ? 0.0f : expf(x1 - M));
  red[t] = e;
  __syncthreads();
  for (int s = 128; s > 0; s >>= 1) {
    if (t < s) red[t] = red[t] + red[t + s];
    __syncthreads();
  }
  if (t == 0) lossb[b] = logf(red[0]) + M - diag;
}

// ---------------------------------------------------------------------------
// Kernel 3: mean over 256 rows -> scalar loss.
// ---------------------------------------------------------------------------
__global__ __launch_bounds__(256) void mean_kernel(
    const float* __restrict__ lossb, float* __restrict__ out)
{
  __shared__ float red[256];
  const int t = threadIdx.x;
  red[t] = lossb[t];
  __syncthreads();
  for (int s = 128; s > 0; s >>= 1) {
    if (t < s) red[t] += red[t + s];
    __syncthreads();
  }
  if (t == 0) out[0] = red[0] * (1.0f / 256.0f);
}

extern "C" void kernel_launch(void* const* d_in, const int* in_sizes, int n_in,
                              void* d_out, int out_size, void* d_ws, size_t ws_size,
                              hipStream_t stream) {
  const float* F   = (const float*)d_in[0];   // fusion_fs [256,4096,64] fp32
  const float* lan = (const float*)d_in[1];   // lan_fs    [256,1,64]   fp32
  float* ws = (float*)d_ws;
  float* max0T = ws;                // [256*256]
  float* max1T = ws + 65536;        // [256*256]
  float* lossb = ws + 131072;       // [256]

  hipFuncSetAttribute((const void*)topk_sim_kernel,
                      hipFuncAttributeMaxDynamicSharedMemorySize, 131072);
  topk_sim_kernel<<<256, 512, 131072, stream>>>(F, lan, max0T, max1T);
  lse_kernel<<<256, 256, 0, stream>>>(max0T, max1T, lossb);
  mean_kernel<<<1, 256, 0, stream>>>(lossb, (float*)d_out);
}

// Round 2
// 151.636 us; speedup vs baseline: 2.9423x; 2.9423x over previous
//
#include <hip/hip_runtime.h>
#include <math.h>

#define BB 256
#define VV 4096
#define DD 64
#define NCH 32          // 32 chunks x 128 rows

typedef __attribute__((ext_vector_type(8))) __bf16 bf16x8;
typedef __attribute__((ext_vector_type(4))) float f32x4;

__device__ __forceinline__ unsigned short bfbits(__bf16 h) {
  return __builtin_bit_cast(unsigned short, h);
}

__device__ __forceinline__ void cvt4pack(float x0, float x1, float x2, float x3,
                                         uint2* hw, uint2* lw) {
  __bf16 h0 = (__bf16)x0, h1 = (__bf16)x1, h2 = (__bf16)x2, h3 = (__bf16)x3;
  __bf16 l0 = (__bf16)(x0 - (float)h0), l1 = (__bf16)(x1 - (float)h1),
         l2 = (__bf16)(x2 - (float)h2), l3 = (__bf16)(x3 - (float)h3);
  hw->x = (unsigned)bfbits(h0) | ((unsigned)bfbits(h1) << 16);
  hw->y = (unsigned)bfbits(h2) | ((unsigned)bfbits(h3) << 16);
  lw->x = (unsigned)bfbits(l0) | ((unsigned)bfbits(l1) << 16);
  lw->y = (unsigned)bfbits(l2) | ((unsigned)bfbits(l3) << 16);
}

// ---------------------------------------------------------------------------
// Kernel 1: per-a block. sim[b,v] = F_a[v,:] . lan[b,:] via split-bf16 MFMA,
// fold per-column top-2 on the fly. Output transposed [a][b].
// ---------------------------------------------------------------------------
__global__ __launch_bounds__(512) void topk_sim_kernel(
    const float* __restrict__ F, const float* __restrict__ lan,
    float* __restrict__ max0T, float* __restrict__ max1T)
{
  extern __shared__ __align__(16) char smem[];   // 64 KB: 2 bufs x (hi 16K + lo 16K)
  const int t = threadIdx.x;
  const int a = blockIdx.x;
  const int wave = t >> 6;
  const int lane = t & 63;
  const int cl = lane & 15;      // row (A) / col (B) within 16x16 tile
  const int g  = lane >> 4;      // k-octet group

  const float4* gF4 = (const float4*)(F + (size_t)a * VV * DD);

  // ---- issue chunk-0 loads early (latency hidden under lan phase) ----
  float4 A0 = gF4[t], A1 = gF4[512 + t], A2 = gF4[1024 + t], A3 = gF4[1536 + t];

  // ---- stage lan [256][64] fp32 into LDS (coalesced) ----
  {
    float4* l4 = (float4*)smem;
    const float4* s4 = (const float4*)lan;
#pragma unroll
    for (int j = 0; j < 8; ++j) l4[j * 512 + t] = s4[j * 512 + t];
  }
  __syncthreads();

  // ---- extract per-wave B fragments (held in regs all kernel) ----
  bf16x8 bh[2][2], bl[2][2];     // [coltile][ksub]
  {
    const float* lf = (const float*)smem;
#pragma unroll
    for (int ct = 0; ct < 2; ++ct)
#pragma unroll
      for (int s = 0; s < 2; ++s) {
        int b = 32 * wave + 16 * ct + cl;
        int k0 = 32 * s + 8 * g;
        float4 u0 = *(const float4*)(lf + b * 64 + k0);
        float4 u1 = *(const float4*)(lf + b * 64 + k0 + 4);
        float xs[8] = {u0.x, u0.y, u0.z, u0.w, u1.x, u1.y, u1.z, u1.w};
        bf16x8 vh, vl;
#pragma unroll
        for (int e = 0; e < 8; ++e) {
          __bf16 h = (__bf16)xs[e];
          vh[e] = h;
          vl[e] = (__bf16)(xs[e] - (float)h);
        }
        bh[ct][s] = vh; bl[ct][s] = vl;
      }
  }
  __syncthreads();

  // ---- staging write: fp32 regs -> hi/lo bf16 planes, XOR-swizzled ----
  const int tl = t & 15, th = t >> 4;
  const int slot = tl >> 1, off8 = (tl & 1) << 3;
  auto write_chunk = [&](int p, float4 v0, float4 v1, float4 v2, float4 v3) {
    char* hiP = smem + p * 32768;
    char* loP = hiP + 16384;
    float4 vv[4] = {v0, v1, v2, v3};
#pragma unroll
    for (int i = 0; i < 4; ++i) {
      int rr = 32 * i + th;                          // row in [0,128)
      int by = rr * 128 + ((slot ^ (rr & 7)) << 4) + off8;
      uint2 hw, lw;
      cvt4pack(vv[i].x, vv[i].y, vv[i].z, vv[i].w, &hw, &lw);
      *(uint2*)(hiP + by) = hw;
      *(uint2*)(loP + by) = lw;
    }
  };

  float m0[2] = {-INFINITY, -INFINITY}, m1[2] = {-INFINITY, -INFINITY};

  auto compute = [&](int p) {
    const char* hiP = smem + p * 32768;
    const char* loP = hiP + 16384;
#pragma unroll
    for (int rt = 0; rt < 8; ++rt) {
      int r = rt * 16 + cl;
      int rx = r & 7;
      int by0 = r * 128 + ((g ^ rx) << 4);           // ksub 0
      int by1 = r * 128 + (((4 + g) ^ rx) << 4);     // ksub 1
      bf16x8 ah0 = *(const bf16x8*)(hiP + by0);
      bf16x8 ah1 = *(const bf16x8*)(hiP + by1);
      bf16x8 al0 = *(const bf16x8*)(loP + by0);
      bf16x8 al1 = *(const bf16x8*)(loP + by1);
      f32x4 acc0 = {0.f, 0.f, 0.f, 0.f}, acc1 = acc0;
      acc0 = __builtin_amdgcn_mfma_f32_16x16x32_bf16(ah0, bh[0][0], acc0, 0, 0, 0);
      acc1 = __builtin_amdgcn_mfma_f32_16x16x32_bf16(ah0, bh[1][0], acc1, 0, 0, 0);
      acc0 = __builtin_amdgcn_mfma_f32_16x16x32_bf16(ah1, bh[0][1], acc0, 0, 0, 0);
      acc1 = __builtin_amdgcn_mfma_f32_16x16x32_bf16(ah1, bh[1][1], acc1, 0, 0, 0);
      acc0 = __builtin_amdgcn_mfma_f32_16x16x32_bf16(ah0, bl[0][0], acc0, 0, 0, 0);
      acc1 = __builtin_amdgcn_mfma_f32_16x16x32_bf16(ah0, bl[1][0], acc1, 0, 0, 0);
      acc0 = __builtin_amdgcn_mfma_f32_16x16x32_bf16(ah1, bl[0][1], acc0, 0, 0, 0);
      acc1 = __builtin_amdgcn_mfma_f32_16x16x32_bf16(ah1, bl[1][1], acc1, 0, 0, 0);
      acc0 = __builtin_amdgcn_mfma_f32_16x16x32_bf16(al0, bh[0][0], acc0, 0, 0, 0);
      acc1 = __builtin_amdgcn_mfma_f32_16x16x32_bf16(al0, bh[1][0], acc1, 0, 0, 0);
      acc0 = __builtin_amdgcn_mfma_f32_16x16x32_bf16(al1, bh[0][1], acc0, 0, 0, 0);
      acc1 = __builtin_amdgcn_mfma_f32_16x16x32_bf16(al1, bh[1][1], acc1, 0, 0, 0);
#pragma unroll
      for (int j = 0; j < 4; ++j) {
        float v = acc0[j];
        float n1 = v > m0[0] ? m0[0] : fmaxf(m1[0], v);
        m0[0] = fmaxf(m0[0], v); m1[0] = n1;
        v = acc1[j];
        n1 = v > m0[1] ? m0[1] : fmaxf(m1[1], v);
        m0[1] = fmaxf(m0[1], v); m1[1] = n1;
      }
    }
  };

  // ---- prologue: chunk 0 into buf0; prefetch chunk 1 ----
  write_chunk(0, A0, A1, A2, A3);
  float4 B0 = gF4[2048 + t], B1 = gF4[2048 + 512 + t],
         B2 = gF4[2048 + 1024 + t], B3 = gF4[2048 + 1536 + t];
  __syncthreads();

  // ---- main loop: 2 chunks per iteration, loads issued at top of compute ----
#pragma unroll 1
  for (int q = 0; q < 16; ++q) {
    const int ch = 2 * q;
    if (ch + 2 < NCH) {
      const float4* src = gF4 + (ch + 2) * 2048 + t;
      A0 = src[0]; A1 = src[512]; A2 = src[1024]; A3 = src[1536];
    }
    compute(0);
    if (ch + 1 < NCH) {
      __syncthreads();
      write_chunk(1, B0, B1, B2, B3);
      __syncthreads();
    }
    if (ch + 3 < NCH) {
      const float4* src = gF4 + (ch + 3) * 2048 + t;
      B0 = src[0]; B1 = src[512]; B2 = src[1024]; B3 = src[1536];
    }
    compute(1);
    if (ch + 2 < NCH) {
      __syncthreads();
      write_chunk(0, A0, A1, A2, A3);
      __syncthreads();
    }
  }

  // ---- cross-lane top-2 merge (rows live in lane>>4 groups) + store ----
#pragma unroll
  for (int ct = 0; ct < 2; ++ct) {
#pragma unroll
    for (int off = 16; off <= 32; off <<= 1) {
      float o0 = __shfl_xor(m0[ct], off);
      float o1 = __shfl_xor(m1[ct], off);
      float n1 = fmaxf(fminf(m0[ct], o0), fmaxf(m1[ct], o1));
      m0[ct] = fmaxf(m0[ct], o0);
      m1[ct] = n1;
    }
    if (lane < 16) {
      int col = 32 * wave + 16 * ct + lane;
      max0T[a * BB + col] = m0[ct];
      max1T[a * BB + col] = m1[ct];
    }
  }
}

// ---------------------------------------------------------------------------
// Kernel 2: per row b, LSE over 511 logits, loss_b = LSE - diag.
// ---------------------------------------------------------------------------
__global__ __launch_bounds__(256) void lse_kernel(
    const float* __restrict__ max0T, const float* __restrict__ max1T,
    float* __restrict__ lossb)
{
  __shared__ float red[256];
  __shared__ float diag;
  const int b = blockIdx.x;
  const int t = threadIdx.x;     // t = a
  float x0 = max0T[t * BB + b];
  float x1 = (t == b) ? -INFINITY : max1T[t * BB + b];
  if (t == b) diag = x0;
  red[t] = fmaxf(x0, x1);
  __syncthreads();
  for (int s = 128; s > 0; s >>= 1) {
    if (t < s) red[t] = fmaxf(red[t], red[t + s]);
    __syncthreads();
  }
  float M = red[0];
  __syncthreads();
  float e = expf(x0 - M) + ((t == b) ? 0.0f : expf(x1 - M));
  red[t] = e;
  __syncthreads();
  for (int s = 128; s > 0; s >>= 1) {
    if (t < s) red[t] = red[t] + red[t + s];
    __syncthreads();
  }
  if (t == 0) lossb[b] = logf(red[0]) + M - diag;
}

__global__ __launch_bounds__(256) void mean_kernel(
    const float* __restrict__ lossb, float* __restrict__ out)
{
  __shared__ float red[256];
  const int t = threadIdx.x;
  red[t] = lossb[t];
  __syncthreads();
  for (int s = 128; s > 0; s >>= 1) {
    if (t < s) red[t] += red[t + s];
    __syncthreads();
  }
  if (t == 0) out[0] = red[0] * (1.0f / 256.0f);
}

extern "C" void kernel_launch(void* const* d_in, const int* in_sizes, int n_in,
                              void* d_out, int out_size, void* d_ws, size_t ws_size,
                              hipStream_t stream) {
  const float* F   = (const float*)d_in[0];   // fusion_fs [256,4096,64] fp32
  const float* lan = (const float*)d_in[1];   // lan_fs    [256,1,64]   fp32
  float* ws = (float*)d_ws;
  float* max0T = ws;                // [256*256]
  float* max1T = ws + 65536;        // [256*256]
  float* lossb = ws + 131072;       // [256]

  hipFuncSetAttribute((const void*)topk_sim_kernel,
                      hipFuncAttributeMaxDynamicSharedMemorySize, 65536);
  topk_sim_kernel<<<256, 512, 65536, stream>>>(F, lan, max0T, max1T);
  lse_kernel<<<256, 256, 0, stream>>>(max0T, max1T, lossb);
  mean_kernel<<<1, 256, 0, stream>>>(lossb, (float*)d_out);
}

// Round 3
// 93.405 us; speedup vs baseline: 4.7766x; 1.6234x over previous
//
#include <hip/hip_runtime.h>
#include <math.h>

#define BB 256
#define VV 4096
#define DD 64

typedef __attribute__((ext_vector_type(8))) _Float16 f16x8;
typedef __attribute__((ext_vector_type(4))) float f32x4;

// ---------------------------------------------------------------------------
// Kernel 1: one block per a (256 blocks, 8 waves). Wave w owns v-rows
// [512w, 512w+512) x ALL 256 b-columns. lan fragments (fp16) live in
// registers; F is loaded straight from global in A-fragment order and
// converted in regs. Main loop: no LDS, no barriers.
// Output transposed: max0T[a*256+b], max1T[a*256+b].
// ---------------------------------------------------------------------------
__global__ __launch_bounds__(512, 2) void topk_sim_kernel(
    const float* __restrict__ F, const float* __restrict__ lan,
    float* __restrict__ max0T, float* __restrict__ max1T)
{
  __shared__ __align__(16) float lsm[BB * DD];   // 64 KB: lan staging, later merge
  const int t = threadIdx.x;
  const int a = blockIdx.x;
  const int wave = t >> 6;
  const int lane = t & 63;
  const int cl = lane & 15;      // A-row / B-col / C-col within 16x16 tile
  const int o  = lane >> 4;      // k-octet group

  // ---- stage lan [256][64] fp32 into LDS (coalesced, one-time) ----
  {
    const float4* s4 = (const float4*)lan;
    float4* l4 = (float4*)lsm;
#pragma unroll
    for (int j = 0; j < 8; ++j) l4[j * 512 + t] = s4[j * 512 + t];
  }
  __syncthreads();

  // ---- B fragments for all 16 column-tiles, fp16, kept in regs ----
  f16x8 bf[16][2];
#pragma unroll
  for (int ct = 0; ct < 16; ++ct)
#pragma unroll
    for (int s = 0; s < 2; ++s) {
      const float* p = lsm + (ct * 16 + cl) * DD + s * 32 + o * 8;
      f16x8 v;
#pragma unroll
      for (int e = 0; e < 8; ++e) v[e] = (_Float16)p[e];
      bf[ct][s] = v;
    }
  __syncthreads();   // all lsm reads done before epilogue reuses it

  float m0[16], m1[16];
#pragma unroll
  for (int ct = 0; ct < 16; ++ct) { m0[ct] = -INFINITY; m1[ct] = -INFINITY; }

  // per-lane base: row = 512*wave + chunk*16 + cl, k-octet o (both ksubs)
  const float* Fa = F + (size_t)a * VV * DD + (size_t)wave * 512 * DD
                    + cl * DD + o * 8;

  float4 c0, c1, c2, c3;
  {
    const float* p = Fa;
    c0 = *(const float4*)(p);      c1 = *(const float4*)(p + 4);
    c2 = *(const float4*)(p + 32); c3 = *(const float4*)(p + 36);
  }

#pragma unroll 1
  for (int ch = 0; ch < 32; ++ch) {
    float4 n0, n1, n2, n3;
    if (ch + 1 < 32) {
      const float* p = Fa + (ch + 1) * 16 * DD;
      n0 = *(const float4*)(p);      n1 = *(const float4*)(p + 4);
      n2 = *(const float4*)(p + 32); n3 = *(const float4*)(p + 36);
    }
    // fp32 -> fp16 A fragments (in regs)
    f16x8 a0, a1;
    a0[0] = (_Float16)c0.x; a0[1] = (_Float16)c0.y;
    a0[2] = (_Float16)c0.z; a0[3] = (_Float16)c0.w;
    a0[4] = (_Float16)c1.x; a0[5] = (_Float16)c1.y;
    a0[6] = (_Float16)c1.z; a0[7] = (_Float16)c1.w;
    a1[0] = (_Float16)c2.x; a1[1] = (_Float16)c2.y;
    a1[2] = (_Float16)c2.z; a1[3] = (_Float16)c2.w;
    a1[4] = (_Float16)c3.x; a1[5] = (_Float16)c3.y;
    a1[6] = (_Float16)c3.z; a1[7] = (_Float16)c3.w;

#pragma unroll
    for (int ct = 0; ct < 16; ++ct) {
      f32x4 acc = {0.f, 0.f, 0.f, 0.f};
      acc = __builtin_amdgcn_mfma_f32_16x16x32_f16(a0, bf[ct][0], acc, 0, 0, 0);
      acc = __builtin_amdgcn_mfma_f32_16x16x32_f16(a1, bf[ct][1], acc, 0, 0, 0);
      // top-2 of the 4 accum values (4 rows, same column)
      float h1 = fmaxf(acc[0], acc[1]), q1 = fminf(acc[0], acc[1]);
      float h2 = fmaxf(acc[2], acc[3]), q2 = fminf(acc[2], acc[3]);
      float M0 = fmaxf(h1, h2);
      float M1 = fmaxf(fminf(h1, h2), fmaxf(q1, q2));
      // merge into running top-2
      float old0 = m0[ct];
      m0[ct] = fmaxf(old0, M0);
      m1[ct] = fmaxf(m1[ct], fmaxf(fminf(old0, M0), M1));
    }
    c0 = n0; c1 = n1; c2 = n2; c3 = n3;
  }

  // ---- merge across the 4 row-groups (lane>>4) within the wave ----
#pragma unroll
  for (int ct = 0; ct < 16; ++ct) {
#pragma unroll
    for (int off = 16; off <= 32; off <<= 1) {
      float p0 = __shfl_xor(m0[ct], off);
      float p1 = __shfl_xor(m1[ct], off);
      float n1 = fmaxf(fminf(m0[ct], p0), fmaxf(m1[ct], p1));
      m0[ct] = fmaxf(m0[ct], p0);
      m1[ct] = n1;
    }
  }

  // ---- cross-wave merge via LDS (reuse lsm) ----
  if (lane < 16) {
#pragma unroll
    for (int ct = 0; ct < 16; ++ct) {
      int col = ct * 16 + lane;
      lsm[(wave * BB + col) * 2 + 0] = m0[ct];
      lsm[(wave * BB + col) * 2 + 1] = m1[ct];
    }
  }
  __syncthreads();
  if (t < BB) {
    float M0 = -INFINITY, M1 = -INFINITY;
#pragma unroll
    for (int w = 0; w < 8; ++w) {
      float a0 = lsm[(w * BB + t) * 2 + 0];
      float a1 = lsm[(w * BB + t) * 2 + 1];
      float n1 = fmaxf(fminf(M0, a0), fmaxf(M1, a1));
      M0 = fmaxf(M0, a0);
      M1 = n1;
    }
    max0T[a * BB + t] = M0;
    max1T[a * BB + t] = M1;
  }
}

// ---------------------------------------------------------------------------
// Kernel 2: per row b, LSE over 511 logits, loss_b = LSE - diag.
// ---------------------------------------------------------------------------
__global__ __launch_bounds__(256) void lse_kernel(
    const float* __restrict__ max0T, const float* __restrict__ max1T,
    float* __restrict__ lossb)
{
  __shared__ float red[256];
  __shared__ float diag;
  const int b = blockIdx.x;
  const int t = threadIdx.x;     // t = a
  float x0 = max0T[t * BB + b];
  float x1 = (t == b) ? -INFINITY : max1T[t * BB + b];
  if (t == b) diag = x0;
  red[t] = fmaxf(x0, x1);
  __syncthreads();
  for (int s = 128; s > 0; s >>= 1) {
    if (t < s) red[t] = fmaxf(red[t], red[t + s]);
    __syncthreads();
  }
  float M = red[0];
  __syncthreads();
  float e = expf(x0 - M) + ((t == b) ? 0.0f : expf(x1 - M));
  red[t] = e;
  __syncthreads();
  for (int s = 128; s > 0; s >>= 1) {
    if (t < s) red[t] = red[t] + red[t + s];
    __syncthreads();
  }
  if (t == 0) lossb[b] = logf(red[0]) + M - diag;
}

__global__ __launch_bounds__(256) void mean_kernel(
    const float* __restrict__ lossb, float* __restrict__ out)
{
  __shared__ float red[256];
  const int t = threadIdx.x;
  red[t] = lossb[t];
  __syncthreads();
  for (int s = 128; s > 0; s >>= 1) {
    if (t < s) red[t] += red[t + s];
    __syncthreads();
  }
  if (t == 0) out[0] = red[0] * (1.0f / 256.0f);
}

extern "C" void kernel_launch(void* const* d_in, const int* in_sizes, int n_in,
                              void* d_out, int out_size, void* d_ws, size_t ws_size,
                              hipStream_t stream) {
  const float* F   = (const float*)d_in[0];   // fusion_fs [256,4096,64] fp32
  const float* lan = (const float*)d_in[1];   // lan_fs    [256,1,64]   fp32
  float* ws = (float*)d_ws;
  float* max0T = ws;                // [256*256]
  float* max1T = ws + 65536;        // [256*256]
  float* lossb = ws + 131072;       // [256]

  topk_sim_kernel<<<256, 512, 0, stream>>>(F, lan, max0T, max1T);
  lse_kernel<<<256, 256, 0, stream>>>(max0T, max1T, lossb);
  mean_kernel<<<1, 256, 0, stream>>>(lossb, (float*)d_out);
}